// Round 16
// baseline (63.539 us; speedup 1.0000x reference)
//
#include <hip/hip_runtime.h>
#include <hip/hip_fp16.h>
#include <math.h>

#define NB  4
#define DD  128
#define HH  128
#define WW  128
#define KS  11
#define PAD 5
#define NF  4             // fields: xbar, ybar, xybar, (x2+y2)bar
#define ZCK 32            // z outputs per K1 block (4 chunks)
#define HCK 32            // h outputs per K2 block (4 chunks)

// Packed intermediate layout: A[n][z][h][q][f*2] fp16 (q = w-pair).
#define QS      8                 // halfs per q-slot (4 fields x 2 voxels)
#define HROW    (64 * QS)         // 512 halfs per h row
#define ZPLANE  (HH * HROW)       // 65536 halfs per z plane

using f32x2 = __attribute__((ext_vector_type(2))) float;
using u32x4 = __attribute__((ext_vector_type(4))) unsigned;

struct GW { float g[KS]; };

static __device__ __forceinline__ f32x2 vfma2(f32x2 a, f32x2 b, f32x2 c) {
    return __builtin_elementwise_fma(a, b, c);
}
static __device__ __forceinline__ unsigned h2u(__half2 v) {
    union { __half2 h; unsigned u; } x; x.h = v; return x.u;
}
static __device__ __forceinline__ f32x2 u2f2(unsigned u) {
    union { unsigned u; __half2 h; } x; x.u = u;
    const float2 f = __half22float2(x.h);
    return (f32x2){f.x, f.y};
}

// Build a buffer SRSRC for one row: base (wave-uniform), num_records bytes
// (stride=0 -> byte bound), word3 = raw dword access. OOB lanes read 0.
static __device__ __forceinline__ u32x4 make_rsrc(const float* p, unsigned bytes) {
    const unsigned long long a = (unsigned long long)p;
    u32x4 r;
    r.x = __builtin_amdgcn_readfirstlane((unsigned)a);
    r.y = __builtin_amdgcn_readfirstlane((unsigned)(a >> 32));
    r.z = bytes;
    r.w = 0x00020000u;
    return r;
}
static __device__ __forceinline__ float2 bload2(u32x4 rsrc, unsigned voff) {
    float2 r;
    asm volatile("buffer_load_dwordx2 %0, %1, %2, 0 offen"
                 : "=v"(r) : "v"(voff), "s"(rsrc));
    return r;
}

// ---------------------------------------------------------------------------
// K1: fields + W-conv + D-conv fused, 2 w-voxels per thread, single-wave
// blocks (64 thr = one h-row), ZCK=32. R16: NO LDS AT ALL — each lane reads
// its 14-float window (7 x buffer_load_dwordx2 per image) straight from the
// L1/L2-resident row. HW bounds check (num_records=512/row, voffset wrap for
// w<0) delivers conv zero-padding for free; invalid z-planes via
// num_records=0. Removes the ds_write->fence->ds_read serial chain that
// pinned R9..R15 at ~44us. W-conv / packed D-chains / packed store = R9.
// ---------------------------------------------------------------------------
__global__ __launch_bounds__(64)
void k1_wd(const float* __restrict__ img1, const float* __restrict__ img2,
           __half* __restrict__ A, GW gw) {
    const int q  = threadIdx.x;    // w-pair == lane
    const int b  = blockIdx.x;
    const int h  = b & 127;
    const int zc = (b >> 7) & 3;
    const int n  = b >> 9;
    const int w0 = q * 2;
    const int z0 = zc * ZCK;

    const long long nhBase  = (long long)n * DD * HH * WW + (long long)h * WW;
    const long long outBase = (long long)n * DD * ZPLANE +
                              (long long)h * HROW + (long long)q * QS;

    // per-lane voffsets for the 7 window pairs (w = w0-6+2i); computed once.
    // For w<0 the unsigned value wraps huge -> HW OOB -> returns 0.
    unsigned vo[7];
    #pragma unroll
    for (int i = 0; i < 7; ++i) vo[i] = (unsigned)((w0 - 6 + 2 * i) * 4);

    f32x2 acc[NF][KS];
    #pragma unroll
    for (int f = 0; f < NF; ++f)
        #pragma unroll
        for (int j = 0; j < KS; ++j) acc[f][j] = (f32x2){0.f, 0.f};

    const int STEPS = ZCK + 2 * PAD;   // 42

    // element e (0..13) = w-coord w0-6+e; pair j holds e=2j (lo), 2j+1 (hi)
    #define ELV(A2, i) ((i) & 1 ? A2[(i) >> 1].y : A2[(i) >> 1].x)

    #define K1_STEP(S, DOST)                                                   \
    {                                                                          \
        const int zi = z0 - PAD + (S);                                         \
        const unsigned rec = (zi >= 0 && zi < DD) ? (WW * 4u) : 0u;            \
        const float* row1 = img1 + nhBase + (long long)zi * (HH * WW);         \
        const float* row2 = img2 + nhBase + (long long)zi * (HH * WW);         \
        const u32x4 d1 = make_rsrc(row1, rec);                                 \
        const u32x4 d2 = make_rsrc(row2, rec);                                 \
        float2 xw[7], yw[7];                                                   \
        _Pragma("unroll")                                                      \
        for (int i = 0; i < 7; ++i) xw[i] = bload2(d1, vo[i]);                 \
        _Pragma("unroll")                                                      \
        for (int i = 0; i < 7; ++i) yw[i] = bload2(d2, vo[i]);                 \
        asm volatile("s_waitcnt vmcnt(0)" ::: "memory");                       \
        __builtin_amdgcn_sched_barrier(0);                                     \
        f32x2 xv2[7], yv2[7], pv2[7], qv2[7];                                  \
        _Pragma("unroll")                                                      \
        for (int i = 0; i < 7; ++i) {                                          \
            xv2[i] = (f32x2){xw[i].x, xw[i].y};                                \
            yv2[i] = (f32x2){yw[i].x, yw[i].y};                                \
            pv2[i] = xv2[i] * yv2[i];                                          \
            qv2[i] = vfma2(yv2[i], yv2[i], xv2[i] * xv2[i]);                   \
        }                                                                      \
        /* W-conv: vox0 uses elements k+1, vox1 uses k+2 */                    \
        float a0x = 0.f, a0y = 0.f, a1x = 0.f, a1y = 0.f;                      \
        float a2x = 0.f, a2y = 0.f, a3x = 0.f, a3y = 0.f;                      \
        _Pragma("unroll")                                                      \
        for (int k = 0; k < KS; ++k) {                                         \
            const float g = gw.g[k];                                           \
            a0x = fmaf(g, ELV(xv2, k + 1), a0x);                               \
            a0y = fmaf(g, ELV(xv2, k + 2), a0y);                               \
            a1x = fmaf(g, ELV(yv2, k + 1), a1x);                               \
            a1y = fmaf(g, ELV(yv2, k + 2), a1y);                               \
            a2x = fmaf(g, ELV(pv2, k + 1), a2x);                               \
            a2y = fmaf(g, ELV(pv2, k + 2), a2y);                               \
            a3x = fmaf(g, ELV(qv2, k + 1), a3x);                               \
            a3y = fmaf(g, ELV(qv2, k + 2), a3y);                               \
        }                                                                      \
        /* packed D-conv shift-accumulator chains */                           \
        f32x2 v[NF];                                                           \
        v[0] = (f32x2){a0x, a0y}; v[1] = (f32x2){a1x, a1y};                    \
        v[2] = (f32x2){a2x, a2y}; v[3] = (f32x2){a3x, a3y};                    \
        _Pragma("unroll")                                                      \
        for (int f = 0; f < NF; ++f) {                                         \
            _Pragma("unroll")                                                  \
            for (int j = KS - 1; j >= 1; --j) {                                \
                const f32x2 gg = {gw.g[j], gw.g[j]};                           \
                acc[f][j] = vfma2(gg, v[f], acc[f][j - 1]);                    \
            }                                                                  \
            const f32x2 g0 = {gw.g[0], gw.g[0]};                               \
            acc[f][0] = g0 * v[f];                                             \
        }                                                                      \
        if (DOST) {                                                            \
            const int zo = z0 + (S) - 2 * PAD;                                 \
            uint4 pk;                                                          \
            pk.x = h2u(__float22half2_rn(                                      \
                       make_float2(acc[0][KS-1].x, acc[0][KS-1].y)));          \
            pk.y = h2u(__float22half2_rn(                                      \
                       make_float2(acc[1][KS-1].x, acc[1][KS-1].y)));          \
            pk.z = h2u(__float22half2_rn(                                      \
                       make_float2(acc[2][KS-1].x, acc[2][KS-1].y)));          \
            pk.w = h2u(__float22half2_rn(                                      \
                       make_float2(acc[3][KS-1].x, acc[3][KS-1].y)));          \
            *(uint4*)(A + outBase + (long long)zo * ZPLANE) = pk;              \
        }                                                                      \
    }

    for (int s = 0; s < 2 * PAD; ++s) {          // warmup, no store
        K1_STEP(s, 0)
    }
    for (int s = 2 * PAD; s < STEPS; ++s) {      // main, store
        K1_STEP(s, 1)
    }
    #undef K1_STEP
    #undef ELV
}

// ---------------------------------------------------------------------------
// K2: R9's known-good form. H-conv (packed f32x2 shift chains) + packed SSIM
// + block reduction. 2 w-voxels per thread; ONE dwordx4 load per step; 2-deep
// prefetch; rcp+NR division. Block = 256 thr = 4 z x 64 q, walks 32 h (+10).
// ---------------------------------------------------------------------------
__global__ __launch_bounds__(256)
void k2_hssim(const __half* __restrict__ A, double* __restrict__ partials,
              GW gw) {
    const int t  = threadIdx.x;
    const int b  = blockIdx.x;
    const int hc = b & 3;
    const int zp = (b >> 2) & 31;
    const int n  = b >> 7;
    const int zl = t >> 6;
    const int q  = t & 63;
    const int z  = zp * 4 + zl;
    const int h0 = hc * HCK;

    const long long colBase =
        ((long long)(n * DD + z)) * ZPLANE + (long long)q * QS;

    f32x2 acc[NF][KS];
    #pragma unroll
    for (int f = 0; f < NF; ++f)
        #pragma unroll
        for (int j = 0; j < KS; ++j) acc[f][j] = (f32x2){0.f, 0.f};

    const int STEPS = HCK + 2 * PAD;   // 42

    uint4 pfA = make_uint4(0u, 0u, 0u, 0u), pfB = pfA;
    {
        const int hi0 = h0 - PAD;
        if (hi0 >= 0)
            pfA = *(const uint4*)(A + colBase + (long long)hi0 * HROW);
        const int hi1 = h0 - PAD + 1;
        if (hi1 >= 0)
            pfB = *(const uint4*)(A + colBase + (long long)hi1 * HROW);
    }

    const f32x2 C1v = {1e-4f, 1e-4f}, C2v = {9e-4f, 9e-4f};
    const f32x2 TWO = {2.f, 2.f};
    f32x2 sum = {0.f, 0.f};

    #define K2_STEP(S, PFC, DOSSIM)                                            \
    {                                                                          \
        f32x2 v[NF];                                                           \
        v[0] = u2f2(PFC.x); v[1] = u2f2(PFC.y);                                \
        v[2] = u2f2(PFC.z); v[3] = u2f2(PFC.w);                                \
        {   /* prefetch row S+2 */                                             \
            const int hi = h0 - PAD + (S) + 2;                                 \
            uint4 nv = make_uint4(0u, 0u, 0u, 0u);                             \
            if ((S) + 2 < STEPS && hi >= 0 && hi < HH)                         \
                nv = *(const uint4*)(A + colBase + (long long)hi * HROW);      \
            PFC = nv;                                                          \
        }                                                                      \
        _Pragma("unroll")                                                      \
        for (int f = 0; f < NF; ++f) {                                         \
            _Pragma("unroll")                                                  \
            for (int j = KS - 1; j >= 1; --j) {                                \
                const f32x2 gg = {gw.g[j], gw.g[j]};                           \
                acc[f][j] = vfma2(gg, v[f], acc[f][j - 1]);                    \
            }                                                                  \
            const f32x2 g0 = {gw.g[0], gw.g[0]};                               \
            acc[f][0] = g0 * v[f];                                             \
        }                                                                      \
        if (DOSSIM) {                                                          \
            const f32x2 mu1 = acc[0][KS - 1], mu2 = acc[1][KS - 1];            \
            const f32x2 mu1s = mu1 * mu1, mu2s = mu2 * mu2, mu12 = mu1 * mu2;  \
            const f32x2 sg12 = acc[2][KS - 1] - mu12;                          \
            const f32x2 sgss = acc[3][KS - 1] - mu1s - mu2s;                   \
            const f32x2 num = vfma2(TWO, mu12, C1v) * vfma2(TWO, sg12, C2v);   \
            const f32x2 den = (mu1s + mu2s + C1v) * (sgss + C2v);              \
            f32x2 rr;                                                          \
            rr.x = __builtin_amdgcn_rcpf(den.x);                               \
            rr.y = __builtin_amdgcn_rcpf(den.y);                               \
            rr = rr * vfma2(-den, rr, TWO);   /* 1 NR step */                  \
            sum = vfma2(num, rr, sum);                                         \
        }                                                                      \
    }

    for (int s2 = 0; s2 < 2 * PAD; s2 += 2) {
        K2_STEP(s2,     pfA, 0)
        K2_STEP(s2 + 1, pfB, 0)
    }
    for (int s2 = 2 * PAD; s2 < STEPS; s2 += 2) {
        K2_STEP(s2,     pfA, 1)
        K2_STEP(s2 + 1, pfB, 1)
    }
    #undef K2_STEP

    __shared__ double red[256];
    red[t] = (double)sum.x + (double)sum.y;
    __syncthreads();
    for (int sft = 128; sft > 0; sft >>= 1) {
        if (t < sft) red[t] += red[t + sft];
        __syncthreads();
    }
    if (t == 0) partials[b] = red[0];
}

// ---------------------------------------------------------------------------
__global__ __launch_bounds__(256)
void k4_reduce(const double* __restrict__ partials, int nPart,
               float* __restrict__ out) {
    __shared__ double red[256];
    const int t = threadIdx.x;
    double s = 0.0;
    for (int i = t; i < nPart; i += 256) s += partials[i];
    red[t] = s;
    __syncthreads();
    for (int sft = 128; sft > 0; sft >>= 1) {
        if (t < sft) red[t] += red[t + sft];
        __syncthreads();
    }
    if (t == 0) out[0] = (float)(red[0] / (double)((long long)NB * DD * HH * WW));
}

// ---------------------------------------------------------------------------
extern "C" void kernel_launch(void* const* d_in, const int* in_sizes, int n_in,
                              void* d_out, int out_size, void* d_ws, size_t ws_size,
                              hipStream_t stream) {
    const float* img1 = (const float*)d_in[0];
    const float* img2 = (const float*)d_in[1];
    float* out = (float*)d_out;

    GW gw;
    {
        double gs[KS], ssum = 0.0;
        for (int i = 0; i < KS; ++i) {
            const double c = (double)(i - KS / 2);
            gs[i] = exp(-c * c / (2.0 * 1.5 * 1.5));
            ssum += gs[i];
        }
        for (int i = 0; i < KS; ++i) gw.g[i] = (float)(gs[i] / ssum);
    }

    __half* A = (__half*)d_ws;   // [n][z][h][q][f*2] fp16, 67 MB
    double* partials =
        (double*)((char*)d_ws + (long long)NB * DD * ZPLANE * sizeof(__half));

    const int nBlocksK1 = NB * HH * (DD / ZCK);   // 2048 single-wave blocks
    const int nBlocksK2 = NB * 32 * (HH / HCK);   // 512 x 256-thr blocks

    k1_wd<<<nBlocksK1, 64, 0, stream>>>(img1, img2, A, gw);
    k2_hssim<<<nBlocksK2, 256, 0, stream>>>(A, partials, gw);
    k4_reduce<<<1, 256, 0, stream>>>(partials, nBlocksK2, out);
}